// Round 13
// baseline (219.267 us; speedup 1.0000x reference)
//
#include <hip/hip_runtime.h>

#define HDIM 128
#define BN_EPS 1e-5f
#define SCAN_BINS 1024
#define NPART 8    // XCD count: target-range partitions for reorder
#define NSLAB 4    // column slabs: 32 cols x 2B = 64B/row/slab; 2.56MB/slab < 4MB XCD L2
#define LSTR 136   // LDS row stride in shorts (mult of 8 -> 16B-aligned rows)

typedef short short8 __attribute__((ext_vector_type(8)));
typedef float floatx4 __attribute__((ext_vector_type(4)));

__device__ __forceinline__ unsigned short f2b(float f) {
    union { float f; unsigned u; } v; v.f = f;
    unsigned r = v.u + 0x7FFFu + ((v.u >> 16) & 1u);   // RNE
    return (unsigned short)(r >> 16);
}

__device__ __forceinline__ float b2f(unsigned short b) {
    union { unsigned u; float f; } v; v.u = (unsigned)b << 16;
    return v.f;
}

// ---------------------------------------------------------------------------
// prep: convert x -> bf16 column slabs xS[s][N][32], W1/W2 -> bf16,
// histogram targets; atomicAdd return = edge's rank in its bucket (free).
// ---------------------------------------------------------------------------
__global__ __launch_bounds__(256) void prep_kernel(
    const float* __restrict__ x, unsigned short* __restrict__ xS, int N,
    const float* __restrict__ W1, const float* __restrict__ W2,
    unsigned short* __restrict__ W1B, unsigned short* __restrict__ W2B,
    const int* __restrict__ eidx, int* __restrict__ hist,
    int* __restrict__ rank, int E)
{
    int tid = blockIdx.x * 256 + threadIdx.x;
    int stride = gridDim.x * 256;
    long n8 = (long)N * (HDIM / 8);
    for (long i = tid; i < n8; i += stride) {
        int n = (int)(i >> 4);          // row
        int u = (int)(i & 15);          // 8-col unit
        int c = u * 8;
        int s = c >> 5;                 // slab
        int off = c & 31;               // col within slab
        const float* src = x + (size_t)n * HDIM + c;
        float4 v0 = *(const float4*)(src);
        float4 v1 = *(const float4*)(src + 4);
        short8 o;
        o[0] = (short)f2b(v0.x); o[1] = (short)f2b(v0.y);
        o[2] = (short)f2b(v0.z); o[3] = (short)f2b(v0.w);
        o[4] = (short)f2b(v1.x); o[5] = (short)f2b(v1.y);
        o[6] = (short)f2b(v1.z); o[7] = (short)f2b(v1.w);
        *(short8*)(xS + ((size_t)s * N + n) * 32 + off) = o;
    }
    for (int i = tid; i < HDIM * HDIM; i += stride) {
        W1B[i] = f2b(W1[i]);
        W2B[i] = f2b(W2[i]);
    }
    for (int e = tid; e < E; e += stride) {
        rank[e] = atomicAdd(&hist[eidx[E + e]], 1);
    }
}

// ---------------------------------------------------------------------------
// Merged single-dispatch scan: block b redundantly sums hist[0..b*1024) for
// its prefix (L2-hot, <=160KB), then scans its own 1024-bin chunk.
// Block 0 also zeroes BN stats.
// ---------------------------------------------------------------------------
__global__ __launch_bounds__(256) void scan_kernel(
    const int* __restrict__ hist, int* __restrict__ offsets,
    float* __restrict__ statSum, int N, int NB)
{
    __shared__ int ts[256];
    int b = blockIdx.x, t = threadIdx.x;
    if (b == 0 && t < 2 * HDIM) statSum[t] = 0.f;

    // block prefix = sum hist[0 .. b*SCAN_BINS)
    int lim = b * SCAN_BINS;
    int pre = 0;
    for (int i = t; i < lim; i += 256) pre += hist[i];
    ts[t] = pre;
    __syncthreads();
    for (int off = 128; off > 0; off >>= 1) {
        if (t < off) ts[t] += ts[t + off];
        __syncthreads();
    }
    int blockPrefix = ts[0];
    __syncthreads();

    // own chunk scan
    int base = b * SCAN_BINS + t * 4;
    int4 h = make_int4(0, 0, 0, 0);
    if (base + 3 < N) {
        h = *(const int4*)(hist + base);
    } else {
        if (base + 0 < N) h.x = hist[base + 0];
        if (base + 1 < N) h.y = hist[base + 1];
        if (base + 2 < N) h.z = hist[base + 2];
    }
    int s = h.x + h.y + h.z + h.w;
    ts[t] = s;
    __syncthreads();
    for (int off = 1; off < 256; off <<= 1) {
        int v = ts[t];
        int add = (t >= off) ? ts[t - off] : 0;
        __syncthreads();
        ts[t] = v + add;
        __syncthreads();
    }
    int excl = blockPrefix + ts[t] - s;
    int4 o;
    o.x = excl;
    o.y = o.x + h.x;
    o.z = o.y + h.y;
    o.w = o.z + h.z;
    if (base + 3 < N) {
        *(int4*)(offsets + base) = o;
    } else {
        if (base + 0 < N) offsets[base + 0] = o.x;
        if (base + 1 < N) offsets[base + 1] = o.y;
        if (base + 2 < N) offsets[base + 2] = o.z;
    }
    if (b == NB - 1 && t == 255) offsets[N] = blockPrefix + ts[255];
}

// Atomic-free reorder: position = offsets[tgt] + rank[e]. XCD-partitioned
// (blockIdx%8 ~ XCD round-robin; perf heuristic only) for write locality.
__global__ __launch_bounds__(256) void reorder_kernel(
    const int* __restrict__ eidx, const int* __restrict__ offsets,
    const int* __restrict__ rank, int* __restrict__ srcSorted,
    int E, int partSize)
{
    int part = blockIdx.x & (NPART - 1);
    int bi = blockIdx.x >> 3;
    int nb = gridDim.x >> 3;
    int lo = part * partSize;
    int hi = lo + partSize;
    int stride = nb * 256;
    for (int e = bi * 256 + threadIdx.x; e < E; e += stride) {
        int t = eidx[E + e];
        if (t >= lo && t < hi) {
            srcSorted[offsets[t] + rank[e]] = eidx[e];
        }
    }
}

// ---------------------------------------------------------------------------
// mega_kernel (64 rows/block):
//   A: slab gather -- for s in 0..3, gather 32-col slab (64B/edge, slab is
//      XCD-L2-resident) for all 64 rows; 4 lanes/row, 4-edge unroll;
//      self-term from xS; write bf16 into sT columns.
//   B: GEMM1; relu+b1 written IN PLACE over the wave's own 16 rows
//   C: GEMM2 + b2 -> out (fp32, pre-BN) + BN stats to global
// ---------------------------------------------------------------------------
__global__ __launch_bounds__(256, 4) void mega_kernel(
    const unsigned short* __restrict__ xS,
    const int* __restrict__ offsets, const int* __restrict__ srcSorted,
    const float* __restrict__ eps,
    const unsigned short* __restrict__ W1B, const float* __restrict__ b1,
    const unsigned short* __restrict__ W2B, const float* __restrict__ b2,
    float* __restrict__ out, float* __restrict__ statSum,
    float* __restrict__ statSqs, int N)
{
    __shared__ unsigned short sT[64 * LSTR];   // agg tile, then h1 in place
    __shared__ float sSum[HDIM];
    __shared__ float sSqs[HDIM];

    int tid = threadIdx.x;
    int rb = blockIdx.x * 64;
    if (tid < HDIM) { sSum[tid] = 0.f; sSqs[tid] = 0.f; }

    // ---- A: slab gather ----
    float coef = 1.0f + eps[0];
    int rloc = tid >> 2;            // 0..63: target row within block
    int lane4 = tid & 3;
    int cis = lane4 * 8;            // col-in-slab
    int row = rb + rloc;
    int beg = 0, end = 0;
    if (row < N) { beg = offsets[row]; end = offsets[row + 1]; }

    #pragma unroll
    for (int s = 0; s < NSLAB; s++) {
        const unsigned short* slab = xS + (size_t)s * N * 32;
        float acc[8] = {0.f, 0.f, 0.f, 0.f, 0.f, 0.f, 0.f, 0.f};
        int e = beg;
        for (; e + 3 < end; e += 4) {
            int i0 = srcSorted[e];
            int i1 = srcSorted[e + 1];
            int i2 = srcSorted[e + 2];
            int i3 = srcSorted[e + 3];
            short8 u0 = *(const short8*)(slab + (size_t)i0 * 32 + cis);
            short8 u1 = *(const short8*)(slab + (size_t)i1 * 32 + cis);
            short8 u2 = *(const short8*)(slab + (size_t)i2 * 32 + cis);
            short8 u3 = *(const short8*)(slab + (size_t)i3 * 32 + cis);
            #pragma unroll
            for (int j = 0; j < 8; j++)
                acc[j] += (b2f((unsigned short)u0[j]) + b2f((unsigned short)u1[j]))
                        + (b2f((unsigned short)u2[j]) + b2f((unsigned short)u3[j]));
        }
        for (; e < end; e++) {
            int si = srcSorted[e];
            short8 u = *(const short8*)(slab + (size_t)si * 32 + cis);
            #pragma unroll
            for (int j = 0; j < 8; j++)
                acc[j] += b2f((unsigned short)u[j]);
        }
        if (row < N) {
            short8 us = *(const short8*)(slab + (size_t)row * 32 + cis);
            #pragma unroll
            for (int j = 0; j < 8; j++)
                acc[j] += coef * b2f((unsigned short)us[j]);
        }
        short8 o;
        #pragma unroll
        for (int j = 0; j < 8; j++) o[j] = (short)f2b(acc[j]);
        *(short8*)(sT + rloc * LSTR + s * 32 + cis) = o;
    }
    __syncthreads();

    // ---- B: GEMM1 from LDS; h1 written in place over the wave's rows ----
    int w = tid >> 6;
    int l = tid & 63;
    int m = l & 15, quad = l >> 4;
    unsigned short* myT = sT + w * 16 * LSTR;

    floatx4 acc1[8];
    #pragma unroll
    for (int t = 0; t < 8; t++) acc1[t] = (floatx4){0.f, 0.f, 0.f, 0.f};
    #pragma unroll
    for (int kk = 0; kk < 4; kk++) {
        int k0 = kk * 32 + quad * 8;
        short8 a = *(const short8*)(myT + m * LSTR + k0);
        #pragma unroll
        for (int t = 0; t < 8; t++) {
            short8 bfr = *(const short8*)(W1B + (size_t)(t * 16 + m) * HDIM + k0);
            acc1[t] = __builtin_amdgcn_mfma_f32_16x16x32_bf16(a, bfr, acc1[t], 0, 0, 0);
        }
    }
    #pragma unroll
    for (int t = 0; t < 8; t++) {
        int colc = t * 16 + m;
        float bs = b1[colc];
        #pragma unroll
        for (int r = 0; r < 4; r++) {
            float v = fmaxf(acc1[t][r] + bs, 0.f);
            myT[(quad * 4 + r) * LSTR + colc] = f2b(v);
        }
    }
    // no barrier needed: wave w only touches its own 16 rows

    // ---- C: GEMM2 from LDS + b2 -> out (pre-BN), BN stats ----
    floatx4 acc2[8];
    #pragma unroll
    for (int t = 0; t < 8; t++) acc2[t] = (floatx4){0.f, 0.f, 0.f, 0.f};
    #pragma unroll
    for (int kk = 0; kk < 4; kk++) {
        int k0 = kk * 32 + quad * 8;
        short8 a = *(const short8*)(myT + m * LSTR + k0);
        #pragma unroll
        for (int t = 0; t < 8; t++) {
            short8 bfr = *(const short8*)(W2B + (size_t)(t * 16 + m) * HDIM + k0);
            acc2[t] = __builtin_amdgcn_mfma_f32_16x16x32_bf16(a, bfr, acc2[t], 0, 0, 0);
        }
    }
    int row0 = rb + w * 16 + quad * 4;
    #pragma unroll
    for (int t = 0; t < 8; t++) {
        int colc = t * 16 + m;
        float bs = b2[colc];
        float cs = 0.f, cq = 0.f;
        #pragma unroll
        for (int r = 0; r < 4; r++) {
            int rw = row0 + r;
            if (rw < N) {
                float v = acc2[t][r] + bs;
                out[(size_t)rw * HDIM + colc] = v;
                cs += v; cq += v * v;
            }
        }
        cs += __shfl_xor(cs, 16, 64);
        cs += __shfl_xor(cs, 32, 64);
        cq += __shfl_xor(cq, 16, 64);
        cq += __shfl_xor(cq, 32, 64);
        if (quad == 0) {
            atomicAdd(&sSum[colc], cs);
            atomicAdd(&sSqs[colc], cq);
        }
    }
    __syncthreads();
    if (tid < HDIM) {
        atomicAdd(&statSum[tid], sSum[tid]);
        atomicAdd(&statSqs[tid], sSqs[tid]);
    }
}

// ---------------------------------------------------------------------------
// BN apply (prep fused): per-block scale/shift in LDS, then float4 in-place
// ---------------------------------------------------------------------------
__global__ __launch_bounds__(256) void bn_apply_kernel(
    float* __restrict__ out, const float* __restrict__ statSum,
    const float* __restrict__ statSqs, const float* __restrict__ gamma,
    const float* __restrict__ beta, int N, long n4)
{
    __shared__ float sSc[HDIM];
    __shared__ float sSh[HDIM];
    int t = threadIdx.x;
    if (t < HDIM) {
        float invN = 1.0f / (float)N;
        float mean = statSum[t] * invN;
        float var = statSqs[t] * invN - mean * mean;
        float sc = gamma[t] * rsqrtf(var + BN_EPS);
        sSc[t] = sc;
        sSh[t] = beta[t] - mean * sc;
    }
    __syncthreads();
    long stride = (long)gridDim.x * 256;
    for (long i = (long)blockIdx.x * 256 + t; i < n4; i += stride) {
        int cg = (int)(i & 31) * 4;
        float4 v = ((float4*)out)[i];
        v.x = fmaxf(v.x * sSc[cg + 0] + sSh[cg + 0], 0.f);
        v.y = fmaxf(v.y * sSc[cg + 1] + sSh[cg + 1], 0.f);
        v.z = fmaxf(v.z * sSc[cg + 2] + sSh[cg + 2], 0.f);
        v.w = fmaxf(v.w * sSc[cg + 3] + sSh[cg + 3], 0.f);
        ((float4*)out)[i] = v;
    }
}

extern "C" void kernel_launch(void* const* d_in, const int* in_sizes, int n_in,
                              void* d_out, int out_size, void* d_ws, size_t ws_size,
                              hipStream_t stream) {
    const float* x     = (const float*)d_in[0];
    const int*   eidx  = (const int*)d_in[1];
    const float* eps   = (const float*)d_in[2];
    const float* W1    = (const float*)d_in[3];
    const float* b1    = (const float*)d_in[4];
    const float* W2    = (const float*)d_in[5];
    const float* b2    = (const float*)d_in[6];
    const float* gamma = (const float*)d_in[7];
    const float* beta  = (const float*)d_in[8];
    float* out = (float*)d_out;

    int N = in_sizes[0] / HDIM;
    int E = in_sizes[1] / 2;
    size_t NH = (size_t)N * HDIM;
    int NB = (N + SCAN_BINS - 1) / SCAN_BINS;
    int NpadOff = (N + 1 + 3) & ~3;
    int partSize = (N + NPART - 1) / NPART;
    long n4 = (long)NH / 4;

    unsigned short* xS   = (unsigned short*)d_ws;   // NH (4 slabs x N x 32)
    unsigned short* W1B  = xS + NH;                 // H*H
    unsigned short* W2B  = W1B + HDIM * HDIM;       // H*H
    float* statSum = (float*)(W2B + HDIM * HDIM);   // H
    float* statSqs = statSum + HDIM;                // H
    int*   hist    = (int*)(statSqs + HDIM);        // N
    int*   offsets = hist + N;                      // NpadOff
    int*   rank    = offsets + NpadOff;             // E
    int*   srcSorted = rank + E;                    // E

    // 1. zero hist
    hipMemsetAsync(hist, 0, (size_t)N * sizeof(int), stream);
    // 2. convert (slab layout) + histogram (rank from atomicAdd return)
    prep_kernel<<<1280, 256, 0, stream>>>(x, xS, N, W1, W2, W1B, W2B, eidx, hist, rank, E);
    // 3. merged single-dispatch scan (+ zero BN stats)
    scan_kernel<<<NB, 256, 0, stream>>>(hist, offsets, statSum, N, NB);
    // 4. atomic-free XCD-partitioned reorder
    reorder_kernel<<<2048, 256, 0, stream>>>(eidx, offsets, rank, srcSorted, E, partSize);
    // 5. slab-gather + GEMM1 + GEMM2 + BN stats
    int gblocks = (N + 63) / 64;
    mega_kernel<<<gblocks, 256, 0, stream>>>(
        xS, offsets, srcSorted, eps, W1B, b1, W2B, b2,
        out, statSum, statSqs, N);
    // 6. BN scale/shift + apply + final ReLU
    bn_apply_kernel<<<2048, 256, 0, stream>>>(
        out, statSum, statSqs, gamma, beta, N, n4);
}